// Round 4
// baseline (3840.722 us; speedup 1.0000x reference)
//
#include <hip/hip_runtime.h>
#include <math.h>
#include <stdint.h>

typedef unsigned short ushort_t;
typedef unsigned int uint_t;

// Problem constants
#define BB 32
#define CC 3
#define IMG 224
#define PP 16
#define DD 768
#define NTOK 197   // 196 patches + cls
#define NPATCH 196
#define NH 12
#define DHEAD 64
#define MLPD 3072
#define NLAYER 12
#define PROJD 512
#define NCLS 1000
#define MTOK (BB * NTOK)      // 6304
#define MPAD 6400             // padded to multiple of 128

typedef __bf16 bf16x8 __attribute__((ext_vector_type(8)));
typedef float floatx4 __attribute__((ext_vector_type(4)));

__device__ __forceinline__ ushort_t f2bf(float f) {
    union { float f; uint_t u; } x; x.f = f;
    uint_t r = x.u + 0x7fff + ((x.u >> 16) & 1);
    return (ushort_t)(r >> 16);
}

// CK-style async global->LDS direct copy, 16B per lane.
// NOTE: LDS dest is wave-uniform base + lane*16B.
__device__ __forceinline__ void async16(void* lds, const void* g) {
    auto* gp = reinterpret_cast<const __attribute__((address_space(1))) uint_t*>(
        reinterpret_cast<uintptr_t>(g));
    auto* lp = reinterpret_cast<__attribute__((address_space(3))) uint_t*>(
        reinterpret_cast<uintptr_t>(lds));
    __builtin_amdgcn_global_load_lds(gp, lp, 16, 0, 0);
}

// ---------------------------------------------------------------------------
// bf16 MFMA NT GEMM: C[m,n] = sum_k A[m,k]*W[n,k]  (A,W bf16; C fp32 or bf16)
// Tile 128x128, K-step 32, 256 threads = 4 waves each computing 64x64.
// 2-phase double-buffered LDS.
// flags: 1 = +bias, 2 = exact gelu, 4 = fp32 accumulate into C, 8 = bf16 out
// ---------------------------------------------------------------------------
__global__ __launch_bounds__(256, 2)
void gemm_bf16(const ushort_t* __restrict__ A, int lda,
               const ushort_t* __restrict__ W, int ldw,
               const float* __restrict__ bias,
               void* __restrict__ Cout, int ldc, int K, int flags)
{
    __shared__ ushort_t sA[2][128 * 32];
    __shared__ ushort_t sB[2][128 * 32];
    const int m0 = blockIdx.y * 128;
    const int n0 = blockIdx.x * 128;
    const int t = threadIdx.x;
    const int wave = t >> 6;
    const int lane = t & 63;
    const int wm = (wave >> 1) * 64;
    const int wn = (wave & 1) * 64;

    floatx4 acc[4][4] = {};

    const int srow = wave * 32 + (lane >> 2);
    const int scol = (lane & 3) * 8;
    const ushort_t* gA0 = A + (long)(m0 + srow) * lda + scol;
    const ushort_t* gA1 = gA0 + (long)16 * lda;
    const ushort_t* gB0 = W + (long)(n0 + srow) * ldw + scol;
    const ushort_t* gB1 = gB0 + (long)16 * ldw;
    const int lo = wave * 1024;

    const int frow = lane & 15;
    const int fk = (lane >> 4) * 8;

    // prologue: stage tile 0 into buf 0
    async16(sA[0] + lo, gA0); async16(sA[0] + lo + 512, gA1);
    async16(sB[0] + lo, gB0); async16(sB[0] + lo + 512, gB1);
    gA0 += 32; gA1 += 32; gB0 += 32; gB1 += 32;
    __syncthreads();                      // vmcnt(0) drain: buf0 ready

    const int nt = K >> 5;
    int cur = 0;
    for (int tt = 0; tt < nt - 1; tt++) {
        // issue next-tile loads into the other buffer (latency hides below)
        const int nxt = cur ^ 1;
        async16(sA[nxt] + lo, gA0); async16(sA[nxt] + lo + 512, gA1);
        async16(sB[nxt] + lo, gB0); async16(sB[nxt] + lo + 512, gB1);
        gA0 += 32; gA1 += 32; gB0 += 32; gB1 += 32;
        // compute current buffer
        bf16x8 af[4], bfr[4];
#pragma unroll
        for (int i = 0; i < 4; i++)
            af[i] = *(const bf16x8*)(sA[cur] + (wm + i * 16 + frow) * 32 + fk);
#pragma unroll
        for (int j = 0; j < 4; j++)
            bfr[j] = *(const bf16x8*)(sB[cur] + (wn + j * 16 + frow) * 32 + fk);
#pragma unroll
        for (int i = 0; i < 4; i++)
#pragma unroll
            for (int j = 0; j < 4; j++)
                acc[i][j] = __builtin_amdgcn_mfma_f32_16x16x32_bf16(
                    af[i], bfr[j], acc[i][j], 0, 0, 0);
        __syncthreads();                  // next buf ready; cur safe to reuse
        cur = nxt;
    }
    // epilogue tile (no staging)
    {
        bf16x8 af[4], bfr[4];
#pragma unroll
        for (int i = 0; i < 4; i++)
            af[i] = *(const bf16x8*)(sA[cur] + (wm + i * 16 + frow) * 32 + fk);
#pragma unroll
        for (int j = 0; j < 4; j++)
            bfr[j] = *(const bf16x8*)(sB[cur] + (wn + j * 16 + frow) * 32 + fk);
#pragma unroll
        for (int i = 0; i < 4; i++)
#pragma unroll
            for (int j = 0; j < 4; j++)
                acc[i][j] = __builtin_amdgcn_mfma_f32_16x16x32_bf16(
                    af[i], bfr[j], acc[i][j], 0, 0, 0);
    }

    const int rbase = m0 + wm + (lane >> 4) * 4;
    const int cbase = n0 + wn + (lane & 15);
#pragma unroll
    for (int j = 0; j < 4; j++) {
        const int cc = cbase + j * 16;
        const float bv = (flags & 1) ? bias[cc] : 0.f;
#pragma unroll
        for (int i = 0; i < 4; i++) {
#pragma unroll
            for (int r = 0; r < 4; r++) {
                const int row = rbase + i * 16 + r;
                float v = acc[i][j][r] + bv;
                if (flags & 2) v = 0.5f * v * (1.0f + erff(v * 0.70710678118654752f));
                const long off = (long)row * ldc + cc;
                if (flags & 4)      ((float*)Cout)[off] += v;
                else if (flags & 8) ((ushort_t*)Cout)[off] = f2bf(v);
                else                ((float*)Cout)[off] = v;
            }
        }
    }
}

// ---------------------------------------------------------------------------
// bf16 MFMA NT GEMM, tile 128x64. 4 waves, each computing 32x64.
// 2-phase double-buffer. SPLIT-K via blockIdx.z (gridDim.z chunks of K):
// occupancy was grid-limited (600 blocks = 2.3/CU, 22%); z=2 -> 1200 blocks
// all co-resident (LDS cap 6/CU), no tail. Accumulate path (flags&4) uses
// atomicAdd when gridDim.z>1; bias added by chunk z==0 only.
// ---------------------------------------------------------------------------
__global__ __launch_bounds__(256, 2)
void gemm_bf16_n64(const ushort_t* __restrict__ A, int lda,
                   const ushort_t* __restrict__ W, int ldw,
                   const float* __restrict__ bias,
                   void* __restrict__ Cout, int ldc, int K, int flags)
{
    __shared__ ushort_t sA[2][128 * 32];
    __shared__ ushort_t sB[2][64 * 32];
    const int m0 = blockIdx.y * 128;
    const int n0 = blockIdx.x * 64;
    const int kz = blockIdx.z;
    const int nz = gridDim.z;
    const int Kc = K / nz;                // must be a multiple of 32
    const int t = threadIdx.x;
    const int wave = t >> 6;
    const int lane = t & 63;
    const int wm = wave * 32;

    floatx4 acc[2][4] = {};

    const int srowA = wave * 32 + (lane >> 2);
    const int srowB = wave * 16 + (lane >> 2);
    const int scol = kz * Kc + (lane & 3) * 8;
    const ushort_t* gA0 = A + (long)(m0 + srowA) * lda + scol;
    const ushort_t* gA1 = gA0 + (long)16 * lda;
    const ushort_t* gB0 = W + (long)(n0 + srowB) * ldw + scol;
    const int loA = wave * 1024;
    const int loB = wave * 512;

    const int frow = lane & 15;
    const int fk = (lane >> 4) * 8;

    // prologue: stage tile 0 into buf 0
    async16(sA[0] + loA, gA0); async16(sA[0] + loA + 512, gA1);
    async16(sB[0] + loB, gB0);
    gA0 += 32; gA1 += 32; gB0 += 32;
    __syncthreads();

    const int nt = Kc >> 5;
    int cur = 0;
    for (int tt = 0; tt < nt - 1; tt++) {
        const int nxt = cur ^ 1;
        async16(sA[nxt] + loA, gA0); async16(sA[nxt] + loA + 512, gA1);
        async16(sB[nxt] + loB, gB0);
        gA0 += 32; gA1 += 32; gB0 += 32;
        bf16x8 af[2], bfr[4];
#pragma unroll
        for (int i = 0; i < 2; i++)
            af[i] = *(const bf16x8*)(sA[cur] + (wm + i * 16 + frow) * 32 + fk);
#pragma unroll
        for (int j = 0; j < 4; j++)
            bfr[j] = *(const bf16x8*)(sB[cur] + (j * 16 + frow) * 32 + fk);
#pragma unroll
        for (int i = 0; i < 2; i++)
#pragma unroll
            for (int j = 0; j < 4; j++)
                acc[i][j] = __builtin_amdgcn_mfma_f32_16x16x32_bf16(
                    af[i], bfr[j], acc[i][j], 0, 0, 0);
        __syncthreads();
        cur = nxt;
    }
    {
        bf16x8 af[2], bfr[4];
#pragma unroll
        for (int i = 0; i < 2; i++)
            af[i] = *(const bf16x8*)(sA[cur] + (wm + i * 16 + frow) * 32 + fk);
#pragma unroll
        for (int j = 0; j < 4; j++)
            bfr[j] = *(const bf16x8*)(sB[cur] + (j * 16 + frow) * 32 + fk);
#pragma unroll
        for (int i = 0; i < 2; i++)
#pragma unroll
            for (int j = 0; j < 4; j++)
                acc[i][j] = __builtin_amdgcn_mfma_f32_16x16x32_bf16(
                    af[i], bfr[j], acc[i][j], 0, 0, 0);
    }

    const int rbase = m0 + wm + (lane >> 4) * 4;
    const int cbase = n0 + (lane & 15);
#pragma unroll
    for (int j = 0; j < 4; j++) {
        const int cc = cbase + j * 16;
        const float bv = ((flags & 1) && kz == 0) ? bias[cc] : 0.f;
#pragma unroll
        for (int i = 0; i < 2; i++) {
#pragma unroll
            for (int r = 0; r < 4; r++) {
                const int row = rbase + i * 16 + r;
                float v = acc[i][j][r] + bv;
                if (flags & 2) v = 0.5f * v * (1.0f + erff(v * 0.70710678118654752f));
                const long off = (long)row * ldc + cc;
                if (flags & 4) {
                    if (nz > 1) atomicAdd(&((float*)Cout)[off], v);
                    else        ((float*)Cout)[off] += v;
                }
                else if (flags & 8) ((ushort_t*)Cout)[off] = f2bf(v);
                else                ((float*)Cout)[off] = v;
            }
        }
    }
}

// ---------------------------------------------------------------------------
// Fused attention. One block per (64-query tile, b*h); 4 waves x 16 rows.
// LDS: sKP holds K [224][72] during S-phase, then (aliased) per-wave P;
// sVt holds V transposed [d][key] with +8-elem skew per 8 d-rows so the
// transpose scatter is bank-conflict-free. Total 62 KB -> 2 blocks/CU.
// ---------------------------------------------------------------------------
#define KP 224      // keys padded to 14*16
#define SK_ST 72    // sK row stride (elems)
#define SV_ST 232   // base row stride (elems) for sVt / sP (+skew)

__device__ __forceinline__ int vt_row(int d) { return d * SV_ST + (d >> 3) * 8; }

__global__ __launch_bounds__(256, 2)
void attn_fused(const ushort_t* __restrict__ QKV, ushort_t* __restrict__ O)
{
    __shared__ ushort_t sKP[KP * SK_ST];            // 32,256 B (aliased by P)
    __shared__ ushort_t sVt[64 * SV_ST + 64];       // 29,952 B

    const int bh = blockIdx.y;
    const int b = bh / NH, h = bh - b * NH;
    const int i0 = blockIdx.x * 64;
    const int t = threadIdx.x;
    const int wave = t >> 6, lane = t & 63;
    const int quad = lane >> 4, l16 = lane & 15;

    const ushort_t* base = QKV + (long)b * NTOK * 2304;

    // ---- stage K [key][d]: uint4 per lane, coalesced
    {
        const int key8 = t >> 3;
        const int d8 = (t & 7) * 8;
        const ushort_t* Kb = base + 768 + h * 64 + d8;
#pragma unroll
        for (int pass = 0; pass < 7; pass++) {
            int key = key8 + pass * 32;
            uint4 val = make_uint4(0, 0, 0, 0);
            if (key < NTOK) val = *(const uint4*)(Kb + (long)key * 2304);
            *(uint4*)(sKP + key * SK_ST + d8) = val;
        }
    }
    // ---- stage V transposed: uint4 global read + 8 skewed b16 scatters
    {
        const int key8 = t >> 3;
        const int d8 = (t & 7) * 8;
        const ushort_t* Vb = base + 1536 + h * 64 + d8;
#pragma unroll
        for (int pass = 0; pass < 7; pass++) {
            int key = key8 + pass * 32;
            union { uint4 v; ushort_t u[8]; } val;
            val.v = make_uint4(0, 0, 0, 0);
            if (key < NTOK) val.v = *(const uint4*)(Vb + (long)key * 2304);
#pragma unroll
            for (int i = 0; i < 8; i++)
                sVt[vt_row(d8 + i) + key] = val.u[i];
        }
    }
    // ---- Q fragments from global (A-layout: m=l16, k=quad*8+j)
    int qrow = i0 + wave * 16 + l16;
    int qr_c = (qrow < NTOK) ? qrow : (NTOK - 1);
    const ushort_t* Qb = base + h * 64;
    bf16x8 aq0 = *(const bf16x8*)(Qb + (long)qr_c * 2304 + quad * 8);
    bf16x8 aq1 = *(const bf16x8*)(Qb + (long)qr_c * 2304 + 32 + quad * 8);

    __syncthreads();

    // ---- S = Q K^T : 14 key tiles x 2 k-steps
    floatx4 sacc[14];
#pragma unroll
    for (int i = 0; i < 14; i++) sacc[i] = (floatx4){0.f, 0.f, 0.f, 0.f};
#pragma unroll
    for (int tile = 0; tile < 14; tile++) {
        const ushort_t* kp = sKP + (tile * 16 + l16) * SK_ST + quad * 8;
        bf16x8 b0 = *(const bf16x8*)(kp);
        bf16x8 b1 = *(const bf16x8*)(kp + 32);
        sacc[tile] = __builtin_amdgcn_mfma_f32_16x16x32_bf16(aq0, b0, sacc[tile], 0, 0, 0);
        sacc[tile] = __builtin_amdgcn_mfma_f32_16x16x32_bf16(aq1, b1, sacc[tile], 0, 0, 0);
    }

    // ---- softmax: row = quad*4 + r; 16 lanes sharing `quad` hold a row
    const float scale = 0.125f;
    float mrow[4], lrow[4];
#pragma unroll
    for (int r = 0; r < 4; r++) mrow[r] = -1e30f;
#pragma unroll
    for (int tile = 0; tile < 14; tile++) {
        int col = tile * 16 + l16;
        bool valid = (col < NTOK);
#pragma unroll
        for (int r = 0; r < 4; r++) {
            float s = valid ? sacc[tile][r] * scale : -1e30f;
            sacc[tile][r] = s;
            mrow[r] = fmaxf(mrow[r], s);
        }
    }
#pragma unroll
    for (int r = 0; r < 4; r++) {
        for (int m = 1; m < 16; m <<= 1)
            mrow[r] = fmaxf(mrow[r], __shfl_xor(mrow[r], m));
        lrow[r] = 0.f;
    }
#pragma unroll
    for (int tile = 0; tile < 14; tile++) {
#pragma unroll
        for (int r = 0; r < 4; r++) {
            float p = expf(sacc[tile][r] - mrow[r]);
            sacc[tile][r] = p;
            lrow[r] += p;
        }
    }
#pragma unroll
    for (int r = 0; r < 4; r++) {
        for (int m = 1; m < 16; m <<= 1)
            lrow[r] += __shfl_xor(lrow[r], m);
        lrow[r] = 1.f / lrow[r];
    }

    // all waves must finish reading sKP (K) before P overwrites it
    __syncthreads();

    // ---- write normalized P (bf16) into per-wave aliased region, skewed rows
    ushort_t* sp = sKP + wave * (16 * SV_ST + 16);
#pragma unroll
    for (int tile = 0; tile < 14; tile++) {
        int col = tile * 16 + l16;
#pragma unroll
        for (int r = 0; r < 4; r++) {
            int m = quad * 4 + r;
            sp[m * SV_ST + (m >> 3) * 8 + col] = f2bf(sacc[tile][r] * lrow[r]);
        }
    }
    // wave-local: LDS writes->reads ordered by lgkmcnt within the wave

    // ---- O = P V : A = sp, B = sVt; 7 k-steps of 32 keys
    floatx4 oacc[4];
#pragma unroll
    for (int i = 0; i < 4; i++) oacc[i] = (floatx4){0.f, 0.f, 0.f, 0.f};
#pragma unroll
    for (int ks = 0; ks < 7; ks++) {
        bf16x8 ap = *(const bf16x8*)(sp + l16 * SV_ST + (l16 >> 3) * 8 + ks * 32 + quad * 8);
#pragma unroll
        for (int nt = 0; nt < 4; nt++) {
            bf16x8 bv = *(const bf16x8*)(sVt + vt_row(nt * 16 + l16) + ks * 32 + quad * 8);
            oacc[nt] = __builtin_amdgcn_mfma_f32_16x16x32_bf16(ap, bv, oacc[nt], 0, 0, 0);
        }
    }
    // ---- write O (bf16) token-major [197*b + row][768]
    int orow0 = i0 + wave * 16 + quad * 4;
#pragma unroll
    for (int nt = 0; nt < 4; nt++) {
        int col = h * 64 + nt * 16 + l16;
#pragma unroll
        for (int r = 0; r < 4; r++) {
            int row = orow0 + r;
            if (row < NTOK)
                O[((long)b * NTOK + row) * DD + col] = f2bf(oacc[nt][r]);
        }
    }
}

// ---------------------------------------------------------------------------
// Small-M (M==32) split-K fp32 NT GEMM for the head.
// Tile: 32(M) x 64(N) x 64(K-chunk). grid = (ceil(N/64), 1, K/64).
// Accumulates into C via atomicAdd; C must be zeroed first (zero_f32).
// Bias (flags&1) added by the z==0 chunk.
// ---------------------------------------------------------------------------
__global__ __launch_bounds__(256)
void gemm_nt_skm32(const float* __restrict__ A, int lda,
                   const float* __restrict__ W, int ldw,
                   const float* __restrict__ bias,
                   float* __restrict__ C, int ldc,
                   int Nout, int flags)
{
    __shared__ float sA[32 * 64];
    __shared__ float sW[64 * 65];
    const int t = threadIdx.x;
    const int n0 = blockIdx.x * 64;
    const int k0 = blockIdx.z * 64;

    // stage A (32 x 64), coalesced: e = m*64 + c
#pragma unroll
    for (int s = 0; s < 8; s++) {
        int e = t + s * 256;
        int m = e >> 6, c = e & 63;
        sA[e] = A[(long)m * lda + k0 + c];
    }
    // stage W (64 x 64), coalesced, rows padded to 65
#pragma unroll
    for (int s = 0; s < 16; s++) {
        int e = t + s * 256;
        int r = e >> 6, c = e & 63;
        int n = n0 + r;
        sW[r * 65 + c] = (n < Nout) ? W[(long)n * ldw + k0 + c] : 0.f;
    }
    __syncthreads();

    const int nl = t & 63;       // output column within tile (per-lane)
    const int mg = t >> 6;       // wave id -> m group (wave-uniform)
    float acc[8] = {};
#pragma unroll
    for (int kk = 0; kk < 64; kk++) {
        float wv = sW[nl * 65 + kk];
#pragma unroll
        for (int i = 0; i < 8; i++)
            acc[i] += sA[(mg * 8 + i) * 64 + kk] * wv;
    }

    const int n = n0 + nl;
    if (n < Nout) {
        const float bv = ((flags & 1) && blockIdx.z == 0) ? bias[n] : 0.f;
#pragma unroll
        for (int i = 0; i < 8; i++) {
            int m = mg * 8 + i;
            atomicAdd(&C[(long)m * ldc + n], acc[i] + bv);
        }
    }
}

// ---------------------------------------------------------------------------
// zero-fill fp32 (graph-capture-safe replacement for hipMemsetAsync)
// ---------------------------------------------------------------------------
__global__ void zero_f32(float* __restrict__ p, int n)
{
    int i = blockIdx.x * 256 + threadIdx.x;
    if (i < n) p[i] = 0.f;
}

// ---------------------------------------------------------------------------
// fp32 -> bf16 bulk convert (n % 4 == 0)
// ---------------------------------------------------------------------------
__global__ void f32_to_bf16(const float* __restrict__ in, ushort_t* __restrict__ out, long n)
{
    long i = ((long)blockIdx.x * 256 + threadIdx.x) * 4;
    if (i >= n) return;
    float4 v = *(const float4*)(in + i);
    ushort4 o;
    o.x = f2bf(v.x); o.y = f2bf(v.y); o.z = f2bf(v.z); o.w = f2bf(v.w);
    *(ushort4*)(out + i) = o;
}

// ---------------------------------------------------------------------------
// LayerNorm over last dim (768), fp32 out.
// ---------------------------------------------------------------------------
__global__ void layernorm_rows(const float* __restrict__ X,
                               const float* __restrict__ w,
                               const float* __restrict__ b,
                               float* __restrict__ Y)
{
    const int r = blockIdx.x;
    const int t = threadIdx.x;
    const float* xr = X + (long)r * DD;
    float x0 = xr[t], x1 = xr[t + 256], x2 = xr[t + 512];
    __shared__ float rs[256], rq[256];
    rs[t] = x0 + x1 + x2;
    rq[t] = x0 * x0 + x1 * x1 + x2 * x2;
    __syncthreads();
    for (int off = 128; off > 0; off >>= 1) {
        if (t < off) { rs[t] += rs[t + off]; rq[t] += rq[t + off]; }
        __syncthreads();
    }
    float mean = rs[0] * (1.f / 768.f);
    float var = rq[0] * (1.f / 768.f) - mean * mean;
    float rstd = rsqrtf(var + 1e-5f);
    float* yr = Y + (long)r * DD;
    yr[t]       = (x0 - mean) * rstd * w[t]       + b[t];
    yr[t + 256] = (x1 - mean) * rstd * w[t + 256] + b[t + 256];
    yr[t + 512] = (x2 - mean) * rstd * w[t + 512] + b[t + 512];
}

// LayerNorm, bf16 out.
__global__ void layernorm_rows_bf16(const float* __restrict__ X,
                                    const float* __restrict__ w,
                                    const float* __restrict__ b,
                                    ushort_t* __restrict__ Y)
{
    const int r = blockIdx.x;
    const int t = threadIdx.x;
    const float* xr = X + (long)r * DD;
    float x0 = xr[t], x1 = xr[t + 256], x2 = xr[t + 512];
    __shared__ float rs[256], rq[256];
    rs[t] = x0 + x1 + x2;
    rq[t] = x0 * x0 + x1 * x1 + x2 * x2;
    __syncthreads();
    for (int off = 128; off > 0; off >>= 1) {
        if (t < off) { rs[t] += rs[t + off]; rq[t] += rq[t + off]; }
        __syncthreads();
    }
    float mean = rs[0] * (1.f / 768.f);
    float var = rq[0] * (1.f / 768.f) - mean * mean;
    float rstd = rsqrtf(var + 1e-5f);
    ushort_t* yr = Y + (long)r * DD;
    yr[t]       = f2bf((x0 - mean) * rstd * w[t]       + b[t]);
    yr[t + 256] = f2bf((x1 - mean) * rstd * w[t + 256] + b[t + 256]);
    yr[t + 512] = f2bf((x2 - mean) * rstd * w[t + 512] + b[t + 512]);
}

// LayerNorm of cls rows only -> pooled (B,768) fp32
__global__ void ln_post_cls(const float* __restrict__ X,
                            const float* __restrict__ w,
                            const float* __restrict__ b,
                            float* __restrict__ pooled)
{
    const int bidx = blockIdx.x;
    const int t = threadIdx.x;
    const float* xr = X + (long)bidx * NTOK * DD;
    float x0 = xr[t], x1 = xr[t + 256], x2 = xr[t + 512];
    __shared__ float rs[256], rq[256];
    rs[t] = x0 + x1 + x2;
    rq[t] = x0 * x0 + x1 * x1 + x2 * x2;
    __syncthreads();
    for (int off = 128; off > 0; off >>= 1) {
        if (t < off) { rs[t] += rs[t + off]; rq[t] += rq[t + off]; }
        __syncthreads();
    }
    float mean = rs[0] * (1.f / 768.f);
    float var = rq[0] * (1.f / 768.f) - mean * mean;
    float rstd = rsqrtf(var + 1e-5f);
    float* yr = pooled + (long)bidx * DD;
    yr[t]       = (x0 - mean) * rstd * w[t]       + b[t];
    yr[t + 256] = (x1 - mean) * rstd * w[t + 256] + b[t + 256];
    yr[t + 512] = (x2 - mean) * rstd * w[t + 512] + b[t + 512];
}

// ---------------------------------------------------------------------------
// im2col -> bf16: x (B,C,224,224) -> patches (B*196, 768)
// ---------------------------------------------------------------------------
__global__ void im2col_bf16(const float* __restrict__ x, ushort_t* __restrict__ Pm)
{
    int idx = blockIdx.x * 256 + threadIdx.x;
    const int total = BB * NPATCH * DD;
    if (idx >= total) return;
    int row = idx / DD;
    int k = idx - row * DD;
    int b = row / NPATCH;
    int p = row - b * NPATCH;
    int py = p / 14, px = p - py * 14;
    int c = k >> 8;
    int rr = k & 255;
    int ph = rr >> 4, pw = rr & 15;
    Pm[idx] = f2bf(x[(((long)b * CC + c) * IMG + (py * 16 + ph)) * IMG + (px * 16 + pw)]);
}

// ---------------------------------------------------------------------------
// assemble: Tmp[b,n,:] = (n==0 ? cls : patch_out[b,n-1,:]) + pos_embed[n,:]
// ---------------------------------------------------------------------------
__global__ void assemble_kernel(const float* __restrict__ tmp,
                                const float* __restrict__ cls,
                                const float* __restrict__ pos,
                                float* __restrict__ Hb)
{
    int idx = blockIdx.x * 256 + threadIdx.x;
    const int total = MTOK * DD;
    if (idx >= total) return;
    int row = idx / DD;
    int d = idx - row * DD;
    int b = row / NTOK;
    int n = row - b * NTOK;
    float v = (n == 0) ? cls[d] : tmp[((long)b * NPATCH + (n - 1)) * DD + d];
    Hb[idx] = v + pos[n * DD + d];
}

// ---------------------------------------------------------------------------
extern "C" void kernel_launch(void* const* d_in, const int* in_sizes, int n_in,
                              void* d_out, int out_size, void* d_ws, size_t ws_size,
                              hipStream_t stream)
{
    const float* x          = (const float*)d_in[0];
    const float* conv_w     = (const float*)d_in[1];
    const float* cls_token  = (const float*)d_in[2];
    const float* pos_embed  = (const float*)d_in[3];
    const float* ln_pre_w   = (const float*)d_in[4];
    const float* ln_pre_b   = (const float*)d_in[5];
    const float* ln1_w      = (const float*)d_in[6];
    const float* ln1_b      = (const float*)d_in[7];
    const float* qkv_w      = (const float*)d_in[8];
    const float* qkv_b      = (const float*)d_in[9];
    const float* attn_pw    = (const float*)d_in[10];
    const float* attn_pb    = (const float*)d_in[11];
    const float* ln2_w      = (const float*)d_in[12];
    const float* ln2_b      = (const float*)d_in[13];
    const float* fc_w       = (const float*)d_in[14];
    const float* fc_b       = (const float*)d_in[15];
    const float* cproj_w    = (const float*)d_in[16];
    const float* cproj_b    = (const float*)d_in[17];
    const float* ln_post_w  = (const float*)d_in[18];
    const float* ln_post_b  = (const float*)d_in[19];
    const float* proj_w     = (const float*)d_in[20];
    const float* head_w     = (const float*)d_in[21];
    const float* head_b     = (const float*)d_in[22];
    float* out = (float*)d_out;

    // -------- workspace layout --------
    char* ws = (char*)d_ws;
    size_t off = 0;
    float*    X     = (float*)(ws + off);    off += (size_t)MPAD * DD * 4;        // residual (fp32)
    ushort_t* Hb    = (ushort_t*)(ws + off); off += (size_t)MPAD * DD * 2;        // bf16 activations
    ushort_t* QKVb  = (ushort_t*)(ws + off); off += (size_t)MPAD * 2304 * 2;      // bf16 qkv
    ushort_t* Hmlp  = (ushort_t*)(ws + off); off += (size_t)MPAD * MLPD * 2;      // bf16 mlp / im2col
    float*    ScF   = (float*)(ws + off);    off += (size_t)(BB * NPATCH) * DD * 4; // patch gemm out
    float*    TmpF  = (float*)(ws + off);    off += (size_t)MPAD * DD * 4;        // assemble out
    ushort_t* Wb    = (ushort_t*)(ws + off); off += (size_t)85524480 * 2;         // bf16 weights
    float*  pooled  = (float*)(ws + off);    off += (size_t)BB * DD * 4;
    float*  z       = (float*)(ws + off);    off += (size_t)BB * PROJD * 4;

    ushort_t* convb  = Wb;
    ushort_t* qkvb   = convb  + 589824;
    ushort_t* aprojb = qkvb   + 21233664;
    ushort_t* fcb    = aprojb + 7077888;
    ushort_t* cprojb = fcb    + 28311552;

    // -------- zero split-K accumulators (kernel, not hipMemsetAsync:
    //          host memset nodes can break graph capture) --------
    zero_f32<<<(BB * PROJD + 255) / 256, 256, 0, stream>>>(z, BB * PROJD);
    zero_f32<<<(BB * NCLS + 255) / 256, 256, 0, stream>>>(out, BB * NCLS);

    // -------- weight conversions --------
    {
        long n;
        n = 589824;   f32_to_bf16<<<(n / 4 + 255) / 256, 256, 0, stream>>>(conv_w,  convb,  n);
        n = 21233664; f32_to_bf16<<<(n / 4 + 255) / 256, 256, 0, stream>>>(qkv_w,   qkvb,   n);
        n = 7077888;  f32_to_bf16<<<(n / 4 + 255) / 256, 256, 0, stream>>>(attn_pw, aprojb, n);
        n = 28311552; f32_to_bf16<<<(n / 4 + 255) / 256, 256, 0, stream>>>(fc_w,    fcb,    n);
        n = 28311552; f32_to_bf16<<<(n / 4 + 255) / 256, 256, 0, stream>>>(cproj_w, cprojb, n);
    }

    // -------- patch embed --------
    {
        int tot = BB * NPATCH * DD;
        im2col_bf16<<<(tot + 255) / 256, 256, 0, stream>>>(x, Hmlp);
        gemm_bf16_n64<<<dim3(DD / 64, 49), 256, 0, stream>>>(
            Hmlp, DD, convb, DD, nullptr, ScF, DD, DD, 0);
        int tot2 = MTOK * DD;
        assemble_kernel<<<(tot2 + 255) / 256, 256, 0, stream>>>(ScF, cls_token, pos_embed, TmpF);
        layernorm_rows<<<MTOK, 256, 0, stream>>>(TmpF, ln_pre_w, ln_pre_b, X);
    }

    // -------- transformer blocks --------
    for (int l = 0; l < NLAYER; l++) {
        layernorm_rows_bf16<<<MTOK, 256, 0, stream>>>(X, ln1_w + l * DD, ln1_b + l * DD, Hb);
        gemm_bf16<<<dim3(2304 / 128, MPAD / 128), 256, 0, stream>>>(
            Hb, DD, qkvb + (long)l * 2304 * DD, DD, qkv_b + l * 2304,
            QKVb, 2304, DD, 1 | 8);
        attn_fused<<<dim3(4, BB * NH), 256, 0, stream>>>(QKVb, Hb);
        gemm_bf16_n64<<<dim3(DD / 64, MPAD / 128, 2), 256, 0, stream>>>(
            Hb, DD, aprojb + (long)l * DD * DD, DD, attn_pb + l * DD,
            X, DD, DD, 1 | 4);
        layernorm_rows_bf16<<<MTOK, 256, 0, stream>>>(X, ln2_w + l * DD, ln2_b + l * DD, Hb);
        gemm_bf16<<<dim3(MLPD / 128, MPAD / 128), 256, 0, stream>>>(
            Hb, DD, fcb + (long)l * MLPD * DD, DD, fc_b + l * MLPD,
            Hmlp, MLPD, DD, 1 | 2 | 8);
        gemm_bf16_n64<<<dim3(DD / 64, MPAD / 128, 2), 256, 0, stream>>>(
            Hmlp, MLPD, cprojb + (long)l * DD * MLPD, MLPD, cproj_b + l * DD,
            X, DD, MLPD, 1 | 4);
    }

    // -------- head (split-K, latency-bound fix: 8/16 blocks -> 96/128) ----
    ln_post_cls<<<BB, 256, 0, stream>>>(X, ln_post_w, ln_post_b, pooled);
    gemm_nt_skm32<<<dim3(PROJD / 64, 1, DD / 64), 256, 0, stream>>>(
        pooled, DD, proj_w, DD, nullptr, z, PROJD, PROJD, 0);
    gemm_nt_skm32<<<dim3((NCLS + 63) / 64, 1, PROJD / 64), 256, 0, stream>>>(
        z, PROJD, head_w, PROJD, head_b, out, NCLS, NCLS, 1);
}

// Round 5
// 3455.704 us; speedup vs baseline: 1.1114x; 1.1114x over previous
//
#include <hip/hip_runtime.h>
#include <math.h>
#include <stdint.h>

typedef unsigned short ushort_t;
typedef unsigned int uint_t;

// Problem constants
#define BB 32
#define CC 3
#define IMG 224
#define PP 16
#define DD 768
#define NTOK 197   // 196 patches + cls
#define NPATCH 196
#define NH 12
#define DHEAD 64
#define MLPD 3072
#define NLAYER 12
#define PROJD 512
#define NCLS 1000
#define MTOK (BB * NTOK)      // 6304
#define MPAD 6400             // padded to multiple of 128

typedef __bf16 bf16x8 __attribute__((ext_vector_type(8)));
typedef float floatx4 __attribute__((ext_vector_type(4)));

__device__ __forceinline__ ushort_t f2bf(float f) {
    union { float f; uint_t u; } x; x.f = f;
    uint_t r = x.u + 0x7fff + ((x.u >> 16) & 1);
    return (ushort_t)(r >> 16);
}

// CK-style async global->LDS direct copy, 16B per lane.
// NOTE: LDS dest is wave-uniform base + lane*16B.
__device__ __forceinline__ void async16(void* lds, const void* g) {
    auto* gp = reinterpret_cast<const __attribute__((address_space(1))) uint_t*>(
        reinterpret_cast<uintptr_t>(g));
    auto* lp = reinterpret_cast<__attribute__((address_space(3))) uint_t*>(
        reinterpret_cast<uintptr_t>(lds));
    __builtin_amdgcn_global_load_lds(gp, lp, 16, 0, 0);
}

// ---------------------------------------------------------------------------
// bf16 MFMA NT GEMM: C[m,n] = sum_k A[m,k]*W[n,k]  (A,W bf16; C fp32 or bf16)
// Tile 128x128, K-step 32, 256 threads = 4 waves each computing 64x64.
// 2-phase double-buffered LDS.
// flags: 1 = +bias, 2 = exact gelu, 4 = fp32 accumulate into C, 8 = bf16 out
// ---------------------------------------------------------------------------
__global__ __launch_bounds__(256, 2)
void gemm_bf16(const ushort_t* __restrict__ A, int lda,
               const ushort_t* __restrict__ W, int ldw,
               const float* __restrict__ bias,
               void* __restrict__ Cout, int ldc, int K, int flags)
{
    __shared__ ushort_t sA[2][128 * 32];
    __shared__ ushort_t sB[2][128 * 32];
    const int m0 = blockIdx.y * 128;
    const int n0 = blockIdx.x * 128;
    const int t = threadIdx.x;
    const int wave = t >> 6;
    const int lane = t & 63;
    const int wm = (wave >> 1) * 64;
    const int wn = (wave & 1) * 64;

    floatx4 acc[4][4] = {};

    const int srow = wave * 32 + (lane >> 2);
    const int scol = (lane & 3) * 8;
    const ushort_t* gA0 = A + (long)(m0 + srow) * lda + scol;
    const ushort_t* gA1 = gA0 + (long)16 * lda;
    const ushort_t* gB0 = W + (long)(n0 + srow) * ldw + scol;
    const ushort_t* gB1 = gB0 + (long)16 * ldw;
    const int lo = wave * 1024;

    const int frow = lane & 15;
    const int fk = (lane >> 4) * 8;

    // prologue: stage tile 0 into buf 0
    async16(sA[0] + lo, gA0); async16(sA[0] + lo + 512, gA1);
    async16(sB[0] + lo, gB0); async16(sB[0] + lo + 512, gB1);
    gA0 += 32; gA1 += 32; gB0 += 32; gB1 += 32;
    __syncthreads();                      // vmcnt(0) drain: buf0 ready

    const int nt = K >> 5;
    int cur = 0;
    for (int tt = 0; tt < nt - 1; tt++) {
        // issue next-tile loads into the other buffer (latency hides below)
        const int nxt = cur ^ 1;
        async16(sA[nxt] + lo, gA0); async16(sA[nxt] + lo + 512, gA1);
        async16(sB[nxt] + lo, gB0); async16(sB[nxt] + lo + 512, gB1);
        gA0 += 32; gA1 += 32; gB0 += 32; gB1 += 32;
        // compute current buffer
        bf16x8 af[4], bfr[4];
#pragma unroll
        for (int i = 0; i < 4; i++)
            af[i] = *(const bf16x8*)(sA[cur] + (wm + i * 16 + frow) * 32 + fk);
#pragma unroll
        for (int j = 0; j < 4; j++)
            bfr[j] = *(const bf16x8*)(sB[cur] + (wn + j * 16 + frow) * 32 + fk);
#pragma unroll
        for (int i = 0; i < 4; i++)
#pragma unroll
            for (int j = 0; j < 4; j++)
                acc[i][j] = __builtin_amdgcn_mfma_f32_16x16x32_bf16(
                    af[i], bfr[j], acc[i][j], 0, 0, 0);
        __syncthreads();                  // next buf ready; cur safe to reuse
        cur = nxt;
    }
    // epilogue tile (no staging)
    {
        bf16x8 af[4], bfr[4];
#pragma unroll
        for (int i = 0; i < 4; i++)
            af[i] = *(const bf16x8*)(sA[cur] + (wm + i * 16 + frow) * 32 + fk);
#pragma unroll
        for (int j = 0; j < 4; j++)
            bfr[j] = *(const bf16x8*)(sB[cur] + (wn + j * 16 + frow) * 32 + fk);
#pragma unroll
        for (int i = 0; i < 4; i++)
#pragma unroll
            for (int j = 0; j < 4; j++)
                acc[i][j] = __builtin_amdgcn_mfma_f32_16x16x32_bf16(
                    af[i], bfr[j], acc[i][j], 0, 0, 0);
    }

    const int rbase = m0 + wm + (lane >> 4) * 4;
    const int cbase = n0 + wn + (lane & 15);
#pragma unroll
    for (int j = 0; j < 4; j++) {
        const int cc = cbase + j * 16;
        const float bv = (flags & 1) ? bias[cc] : 0.f;
#pragma unroll
        for (int i = 0; i < 4; i++) {
#pragma unroll
            for (int r = 0; r < 4; r++) {
                const int row = rbase + i * 16 + r;
                float v = acc[i][j][r] + bv;
                if (flags & 2) v = 0.5f * v * (1.0f + erff(v * 0.70710678118654752f));
                const long off = (long)row * ldc + cc;
                if (flags & 4)      ((float*)Cout)[off] += v;
                else if (flags & 8) ((ushort_t*)Cout)[off] = f2bf(v);
                else                ((float*)Cout)[off] = v;
            }
        }
    }
}

// ---------------------------------------------------------------------------
// bf16 MFMA NT GEMM, tile 128x64, K-step 64 (BK=64), 4 waves x 32x64 each.
// Round-4 redesign from counters: split-K doubled occupancy with ZERO core
// speedup -> not latency-bound; 5.5M LDS bank-conflict cycles + m233-style
// per-step barrier drain are the cost. So:
//  (a) BK 32->64: halves barrier/drain count, 16 MFMA + 12 ds_read per phase.
//  (b) XOR-swizzle chunk^=(row&7): at 128B row stride the fragment read is a
//      16-way conflict; swizzle makes it 2-way (free). global_load_lds writes
//      linearly, so the swizzle is applied on the GLOBAL SOURCE address
//      (pre-swizzle) and on the LDS READ (same involution) — rule #21.
// LDS 48KB -> 3 blocks/CU (>= 2.34 grid demand). No split-K (reverted).
// flags: 1 = +bias, 2 = exact gelu, 4 = fp32 accumulate into C, 8 = bf16 out
// ---------------------------------------------------------------------------
__global__ __launch_bounds__(256, 2)
void gemm_bf16_n64(const ushort_t* __restrict__ A, int lda,
                   const ushort_t* __restrict__ W, int ldw,
                   const float* __restrict__ bias,
                   void* __restrict__ Cout, int ldc, int K, int flags)
{
    __shared__ ushort_t sA[2][128 * 64];   // 32 KB
    __shared__ ushort_t sB[2][64 * 64];    // 16 KB
    const int m0 = blockIdx.y * 128;
    const int n0 = blockIdx.x * 64;
    const int t = threadIdx.x;
    const int wave = t >> 6;
    const int lane = t & 63;
    const int wm = wave * 32;

    floatx4 acc[2][4] = {};

    // staging: per async16 round, 64 lanes cover 8 rows x 128B.
    // lane l -> row-in-round = l>>3, dest 16B-chunk = l&7.
    // source chunk pre-swizzled: (l&7) ^ (row&7), row&7 == l>>3 here.
    const int lrow = lane >> 3;                  // 0..7
    const int lchunk = (lane & 7) ^ lrow;        // pre-swizzled source chunk
    const ushort_t* gA = A + (long)(m0 + wave * 32 + lrow) * lda + lchunk * 8;
    const ushort_t* gB = W + (long)(n0 + wave * 16 + lrow) * ldw + lchunk * 8;

    const int frow = lane & 15;
    const int quad = lane >> 4;                  // 0..3
    const int s7 = frow & 7;                     // read-side swizzle key
    const int ck0 = ((0 + quad) ^ s7) * 8;       // kk=0 chunk offset (elems)
    const int ck1 = ((4 + quad) ^ s7) * 8;       // kk=1 chunk offset

    auto stage = [&](int buf) {
        ushort_t* dA = sA[buf] + wave * 2048;    // 32 rows x 64 elems
        ushort_t* dB = sB[buf] + wave * 1024;    // 16 rows x 64 elems
        async16(dA,        gA);
        async16(dA + 512,  gA + (long)8  * lda);
        async16(dA + 1024, gA + (long)16 * lda);
        async16(dA + 1536, gA + (long)24 * lda);
        async16(dB,        gB);
        async16(dB + 512,  gB + (long)8  * ldw);
        gA += 64; gB += 64;
    };
    auto compute = [&](const ushort_t* bA, const ushort_t* bB) {
        bf16x8 a0[2], a1[2], b0[4], b1[4];
#pragma unroll
        for (int i = 0; i < 2; i++) {
            const ushort_t* rp = bA + (wm + i * 16 + frow) * 64;
            a0[i] = *(const bf16x8*)(rp + ck0);
            a1[i] = *(const bf16x8*)(rp + ck1);
        }
#pragma unroll
        for (int j = 0; j < 4; j++) {
            const ushort_t* rp = bB + (j * 16 + frow) * 64;
            b0[j] = *(const bf16x8*)(rp + ck0);
            b1[j] = *(const bf16x8*)(rp + ck1);
        }
#pragma unroll
        for (int i = 0; i < 2; i++)
#pragma unroll
            for (int j = 0; j < 4; j++) {
                acc[i][j] = __builtin_amdgcn_mfma_f32_16x16x32_bf16(
                    a0[i], b0[j], acc[i][j], 0, 0, 0);
                acc[i][j] = __builtin_amdgcn_mfma_f32_16x16x32_bf16(
                    a1[i], b1[j], acc[i][j], 0, 0, 0);
            }
    };

    // prologue
    stage(0);
    __syncthreads();

    const int nt = K >> 6;
    int cur = 0;
    for (int tt = 0; tt < nt - 1; tt++) {
        const int nxt = cur ^ 1;
        stage(nxt);                  // issue loads first: latency hides below
        compute(sA[cur], sB[cur]);
        __syncthreads();
        cur = nxt;
    }
    compute(sA[cur], sB[cur]);       // epilogue tile

    const int rbase = m0 + wm + (lane >> 4) * 4;
    const int cbase = n0 + (lane & 15);
#pragma unroll
    for (int j = 0; j < 4; j++) {
        const int cc = cbase + j * 16;
        const float bv = (flags & 1) ? bias[cc] : 0.f;
#pragma unroll
        for (int i = 0; i < 2; i++) {
#pragma unroll
            for (int r = 0; r < 4; r++) {
                const int row = rbase + i * 16 + r;
                float v = acc[i][j][r] + bv;
                if (flags & 2) v = 0.5f * v * (1.0f + erff(v * 0.70710678118654752f));
                const long off = (long)row * ldc + cc;
                if (flags & 4)      ((float*)Cout)[off] += v;
                else if (flags & 8) ((ushort_t*)Cout)[off] = f2bf(v);
                else                ((float*)Cout)[off] = v;
            }
        }
    }
}

// ---------------------------------------------------------------------------
// Fused attention. One block per (64-query tile, b*h); 4 waves x 16 rows.
// LDS: sKP holds K [224][72] during S-phase, then (aliased) per-wave P;
// sVt holds V transposed [d][key] with +8-elem skew per 8 d-rows so the
// transpose scatter is bank-conflict-free. Total 62 KB -> 2 blocks/CU.
// ---------------------------------------------------------------------------
#define KP 224      // keys padded to 14*16
#define SK_ST 72    // sK row stride (elems)
#define SV_ST 232   // base row stride (elems) for sVt / sP (+skew)

__device__ __forceinline__ int vt_row(int d) { return d * SV_ST + (d >> 3) * 8; }

__global__ __launch_bounds__(256, 2)
void attn_fused(const ushort_t* __restrict__ QKV, ushort_t* __restrict__ O)
{
    __shared__ ushort_t sKP[KP * SK_ST];            // 32,256 B (aliased by P)
    __shared__ ushort_t sVt[64 * SV_ST + 64];       // 29,952 B

    const int bh = blockIdx.y;
    const int b = bh / NH, h = bh - b * NH;
    const int i0 = blockIdx.x * 64;
    const int t = threadIdx.x;
    const int wave = t >> 6, lane = t & 63;
    const int quad = lane >> 4, l16 = lane & 15;

    const ushort_t* base = QKV + (long)b * NTOK * 2304;

    // ---- stage K [key][d]: uint4 per lane, coalesced
    {
        const int key8 = t >> 3;
        const int d8 = (t & 7) * 8;
        const ushort_t* Kb = base + 768 + h * 64 + d8;
#pragma unroll
        for (int pass = 0; pass < 7; pass++) {
            int key = key8 + pass * 32;
            uint4 val = make_uint4(0, 0, 0, 0);
            if (key < NTOK) val = *(const uint4*)(Kb + (long)key * 2304);
            *(uint4*)(sKP + key * SK_ST + d8) = val;
        }
    }
    // ---- stage V transposed: uint4 global read + 8 skewed b16 scatters
    {
        const int key8 = t >> 3;
        const int d8 = (t & 7) * 8;
        const ushort_t* Vb = base + 1536 + h * 64 + d8;
#pragma unroll
        for (int pass = 0; pass < 7; pass++) {
            int key = key8 + pass * 32;
            union { uint4 v; ushort_t u[8]; } val;
            val.v = make_uint4(0, 0, 0, 0);
            if (key < NTOK) val.v = *(const uint4*)(Vb + (long)key * 2304);
#pragma unroll
            for (int i = 0; i < 8; i++)
                sVt[vt_row(d8 + i) + key] = val.u[i];
        }
    }
    // ---- Q fragments from global (A-layout: m=l16, k=quad*8+j)
    int qrow = i0 + wave * 16 + l16;
    int qr_c = (qrow < NTOK) ? qrow : (NTOK - 1);
    const ushort_t* Qb = base + h * 64;
    bf16x8 aq0 = *(const bf16x8*)(Qb + (long)qr_c * 2304 + quad * 8);
    bf16x8 aq1 = *(const bf16x8*)(Qb + (long)qr_c * 2304 + 32 + quad * 8);

    __syncthreads();

    // ---- S = Q K^T : 14 key tiles x 2 k-steps
    floatx4 sacc[14];
#pragma unroll
    for (int i = 0; i < 14; i++) sacc[i] = (floatx4){0.f, 0.f, 0.f, 0.f};
#pragma unroll
    for (int tile = 0; tile < 14; tile++) {
        const ushort_t* kp = sKP + (tile * 16 + l16) * SK_ST + quad * 8;
        bf16x8 b0 = *(const bf16x8*)(kp);
        bf16x8 b1 = *(const bf16x8*)(kp + 32);
        sacc[tile] = __builtin_amdgcn_mfma_f32_16x16x32_bf16(aq0, b0, sacc[tile], 0, 0, 0);
        sacc[tile] = __builtin_amdgcn_mfma_f32_16x16x32_bf16(aq1, b1, sacc[tile], 0, 0, 0);
    }

    // ---- softmax: row = quad*4 + r; 16 lanes sharing `quad` hold a row
    const float scale = 0.125f;
    float mrow[4], lrow[4];
#pragma unroll
    for (int r = 0; r < 4; r++) mrow[r] = -1e30f;
#pragma unroll
    for (int tile = 0; tile < 14; tile++) {
        int col = tile * 16 + l16;
        bool valid = (col < NTOK);
#pragma unroll
        for (int r = 0; r < 4; r++) {
            float s = valid ? sacc[tile][r] * scale : -1e30f;
            sacc[tile][r] = s;
            mrow[r] = fmaxf(mrow[r], s);
        }
    }
#pragma unroll
    for (int r = 0; r < 4; r++) {
        for (int m = 1; m < 16; m <<= 1)
            mrow[r] = fmaxf(mrow[r], __shfl_xor(mrow[r], m));
        lrow[r] = 0.f;
    }
#pragma unroll
    for (int tile = 0; tile < 14; tile++) {
#pragma unroll
        for (int r = 0; r < 4; r++) {
            float p = expf(sacc[tile][r] - mrow[r]);
            sacc[tile][r] = p;
            lrow[r] += p;
        }
    }
#pragma unroll
    for (int r = 0; r < 4; r++) {
        for (int m = 1; m < 16; m <<= 1)
            lrow[r] += __shfl_xor(lrow[r], m);
        lrow[r] = 1.f / lrow[r];
    }

    // all waves must finish reading sKP (K) before P overwrites it
    __syncthreads();

    // ---- write normalized P (bf16) into per-wave aliased region, skewed rows
    ushort_t* sp = sKP + wave * (16 * SV_ST + 16);
#pragma unroll
    for (int tile = 0; tile < 14; tile++) {
        int col = tile * 16 + l16;
#pragma unroll
        for (int r = 0; r < 4; r++) {
            int m = quad * 4 + r;
            sp[m * SV_ST + (m >> 3) * 8 + col] = f2bf(sacc[tile][r] * lrow[r]);
        }
    }
    // wave-local: LDS writes->reads ordered by lgkmcnt within the wave

    // ---- O = P V : A = sp, B = sVt; 7 k-steps of 32 keys
    floatx4 oacc[4];
#pragma unroll
    for (int i = 0; i < 4; i++) oacc[i] = (floatx4){0.f, 0.f, 0.f, 0.f};
#pragma unroll
    for (int ks = 0; ks < 7; ks++) {
        bf16x8 ap = *(const bf16x8*)(sp + l16 * SV_ST + (l16 >> 3) * 8 + ks * 32 + quad * 8);
#pragma unroll
        for (int nt = 0; nt < 4; nt++) {
            bf16x8 bv = *(const bf16x8*)(sVt + vt_row(nt * 16 + l16) + ks * 32 + quad * 8);
            oacc[nt] = __builtin_amdgcn_mfma_f32_16x16x32_bf16(ap, bv, oacc[nt], 0, 0, 0);
        }
    }
    // ---- write O (bf16) token-major [197*b + row][768]
    int orow0 = i0 + wave * 16 + quad * 4;
#pragma unroll
    for (int nt = 0; nt < 4; nt++) {
        int col = h * 64 + nt * 16 + l16;
#pragma unroll
        for (int r = 0; r < 4; r++) {
            int row = orow0 + r;
            if (row < NTOK)
                O[((long)b * NTOK + row) * DD + col] = f2bf(oacc[nt][r]);
        }
    }
}

// ---------------------------------------------------------------------------
// Small-M (M==32) split-K fp32 NT GEMM for the head.
// Tile: 32(M) x 64(N) x 64(K-chunk). grid = (ceil(N/64), 1, K/64).
// Accumulates into C via atomicAdd; C must be zeroed first (zero_f32).
// Bias (flags&1) added by the z==0 chunk.
// ---------------------------------------------------------------------------
__global__ __launch_bounds__(256)
void gemm_nt_skm32(const float* __restrict__ A, int lda,
                   const float* __restrict__ W, int ldw,
                   const float* __restrict__ bias,
                   float* __restrict__ C, int ldc,
                   int Nout, int flags)
{
    __shared__ float sA[32 * 64];
    __shared__ float sW[64 * 65];
    const int t = threadIdx.x;
    const int n0 = blockIdx.x * 64;
    const int k0 = blockIdx.z * 64;

    // stage A (32 x 64), coalesced: e = m*64 + c
#pragma unroll
    for (int s = 0; s < 8; s++) {
        int e = t + s * 256;
        int m = e >> 6, c = e & 63;
        sA[e] = A[(long)m * lda + k0 + c];
    }
    // stage W (64 x 64), coalesced, rows padded to 65
#pragma unroll
    for (int s = 0; s < 16; s++) {
        int e = t + s * 256;
        int r = e >> 6, c = e & 63;
        int n = n0 + r;
        sW[r * 65 + c] = (n < Nout) ? W[(long)n * ldw + k0 + c] : 0.f;
    }
    __syncthreads();

    const int nl = t & 63;       // output column within tile (per-lane)
    const int mg = t >> 6;       // wave id -> m group (wave-uniform)
    float acc[8] = {};
#pragma unroll
    for (int kk = 0; kk < 64; kk++) {
        float wv = sW[nl * 65 + kk];
#pragma unroll
        for (int i = 0; i < 8; i++)
            acc[i] += sA[(mg * 8 + i) * 64 + kk] * wv;
    }

    const int n = n0 + nl;
    if (n < Nout) {
        const float bv = ((flags & 1) && blockIdx.z == 0) ? bias[n] : 0.f;
#pragma unroll
        for (int i = 0; i < 8; i++) {
            int m = mg * 8 + i;
            atomicAdd(&C[(long)m * ldc + n], acc[i] + bv);
        }
    }
}

// ---------------------------------------------------------------------------
// zero-fill fp32 (graph-capture-safe replacement for hipMemsetAsync)
// ---------------------------------------------------------------------------
__global__ void zero_f32(float* __restrict__ p, int n)
{
    int i = blockIdx.x * 256 + threadIdx.x;
    if (i < n) p[i] = 0.f;
}

// ---------------------------------------------------------------------------
// fp32 -> bf16 bulk convert (n % 4 == 0)
// ---------------------------------------------------------------------------
__global__ void f32_to_bf16(const float* __restrict__ in, ushort_t* __restrict__ out, long n)
{
    long i = ((long)blockIdx.x * 256 + threadIdx.x) * 4;
    if (i >= n) return;
    float4 v = *(const float4*)(in + i);
    ushort4 o;
    o.x = f2bf(v.x); o.y = f2bf(v.y); o.z = f2bf(v.z); o.w = f2bf(v.w);
    *(ushort4*)(out + i) = o;
}

// ---------------------------------------------------------------------------
// LayerNorm over last dim (768), fp32 out.
// ---------------------------------------------------------------------------
__global__ void layernorm_rows(const float* __restrict__ X,
                               const float* __restrict__ w,
                               const float* __restrict__ b,
                               float* __restrict__ Y)
{
    const int r = blockIdx.x;
    const int t = threadIdx.x;
    const float* xr = X + (long)r * DD;
    float x0 = xr[t], x1 = xr[t + 256], x2 = xr[t + 512];
    __shared__ float rs[256], rq[256];
    rs[t] = x0 + x1 + x2;
    rq[t] = x0 * x0 + x1 * x1 + x2 * x2;
    __syncthreads();
    for (int off = 128; off > 0; off >>= 1) {
        if (t < off) { rs[t] += rs[t + off]; rq[t] += rq[t + off]; }
        __syncthreads();
    }
    float mean = rs[0] * (1.f / 768.f);
    float var = rq[0] * (1.f / 768.f) - mean * mean;
    float rstd = rsqrtf(var + 1e-5f);
    float* yr = Y + (long)r * DD;
    yr[t]       = (x0 - mean) * rstd * w[t]       + b[t];
    yr[t + 256] = (x1 - mean) * rstd * w[t + 256] + b[t + 256];
    yr[t + 512] = (x2 - mean) * rstd * w[t + 512] + b[t + 512];
}

// LayerNorm, bf16 out.
__global__ void layernorm_rows_bf16(const float* __restrict__ X,
                                    const float* __restrict__ w,
                                    const float* __restrict__ b,
                                    ushort_t* __restrict__ Y)
{
    const int r = blockIdx.x;
    const int t = threadIdx.x;
    const float* xr = X + (long)r * DD;
    float x0 = xr[t], x1 = xr[t + 256], x2 = xr[t + 512];
    __shared__ float rs[256], rq[256];
    rs[t] = x0 + x1 + x2;
    rq[t] = x0 * x0 + x1 * x1 + x2 * x2;
    __syncthreads();
    for (int off = 128; off > 0; off >>= 1) {
        if (t < off) { rs[t] += rs[t + off]; rq[t] += rq[t + off]; }
        __syncthreads();
    }
    float mean = rs[0] * (1.f / 768.f);
    float var = rq[0] * (1.f / 768.f) - mean * mean;
    float rstd = rsqrtf(var + 1e-5f);
    ushort_t* yr = Y + (long)r * DD;
    yr[t]       = f2bf((x0 - mean) * rstd * w[t]       + b[t]);
    yr[t + 256] = f2bf((x1 - mean) * rstd * w[t + 256] + b[t + 256]);
    yr[t + 512] = f2bf((x2 - mean) * rstd * w[t + 512] + b[t + 512]);
}

// LayerNorm of cls rows only -> pooled (B,768) fp32
__global__ void ln_post_cls(const float* __restrict__ X,
                            const float* __restrict__ w,
                            const float* __restrict__ b,
                            float* __restrict__ pooled)
{
    const int bidx = blockIdx.x;
    const int t = threadIdx.x;
    const float* xr = X + (long)bidx * NTOK * DD;
    float x0 = xr[t], x1 = xr[t + 256], x2 = xr[t + 512];
    __shared__ float rs[256], rq[256];
    rs[t] = x0 + x1 + x2;
    rq[t] = x0 * x0 + x1 * x1 + x2 * x2;
    __syncthreads();
    for (int off = 128; off > 0; off >>= 1) {
        if (t < off) { rs[t] += rs[t + off]; rq[t] += rq[t + off]; }
        __syncthreads();
    }
    float mean = rs[0] * (1.f / 768.f);
    float var = rq[0] * (1.f / 768.f) - mean * mean;
    float rstd = rsqrtf(var + 1e-5f);
    float* yr = pooled + (long)bidx * DD;
    yr[t]       = (x0 - mean) * rstd * w[t]       + b[t];
    yr[t + 256] = (x1 - mean) * rstd * w[t + 256] + b[t + 256];
    yr[t + 512] = (x2 - mean) * rstd * w[t + 512] + b[t + 512];
}

// ---------------------------------------------------------------------------
// im2col -> bf16: x (B,C,224,224) -> patches (B*196, 768)
// ---------------------------------------------------------------------------
__global__ void im2col_bf16(const float* __restrict__ x, ushort_t* __restrict__ Pm)
{
    int idx = blockIdx.x * 256 + threadIdx.x;
    const int total = BB * NPATCH * DD;
    if (idx >= total) return;
    int row = idx / DD;
    int k = idx - row * DD;
    int b = row / NPATCH;
    int p = row - b * NPATCH;
    int py = p / 14, px = p - py * 14;
    int c = k >> 8;
    int rr = k & 255;
    int ph = rr >> 4, pw = rr & 15;
    Pm[idx] = f2bf(x[(((long)b * CC + c) * IMG + (py * 16 + ph)) * IMG + (px * 16 + pw)]);
}

// ---------------------------------------------------------------------------
// assemble: Tmp[b,n,:] = (n==0 ? cls : patch_out[b,n-1,:]) + pos_embed[n,:]
// ---------------------------------------------------------------------------
__global__ void assemble_kernel(const float* __restrict__ tmp,
                                const float* __restrict__ cls,
                                const float* __restrict__ pos,
                                float* __restrict__ Hb)
{
    int idx = blockIdx.x * 256 + threadIdx.x;
    const int total = MTOK * DD;
    if (idx >= total) return;
    int row = idx / DD;
    int d = idx - row * DD;
    int b = row / NTOK;
    int n = row - b * NTOK;
    float v = (n == 0) ? cls[d] : tmp[((long)b * NPATCH + (n - 1)) * DD + d];
    Hb[idx] = v + pos[n * DD + d];
}

// ---------------------------------------------------------------------------
extern "C" void kernel_launch(void* const* d_in, const int* in_sizes, int n_in,
                              void* d_out, int out_size, void* d_ws, size_t ws_size,
                              hipStream_t stream)
{
    const float* x          = (const float*)d_in[0];
    const float* conv_w     = (const float*)d_in[1];
    const float* cls_token  = (const float*)d_in[2];
    const float* pos_embed  = (const float*)d_in[3];
    const float* ln_pre_w   = (const float*)d_in[4];
    const float* ln_pre_b   = (const float*)d_in[5];
    const float* ln1_w      = (const float*)d_in[6];
    const float* ln1_b      = (const float*)d_in[7];
    const float* qkv_w      = (const float*)d_in[8];
    const float* qkv_b      = (const float*)d_in[9];
    const float* attn_pw    = (const float*)d_in[10];
    const float* attn_pb    = (const float*)d_in[11];
    const float* ln2_w      = (const float*)d_in[12];
    const float* ln2_b      = (const float*)d_in[13];
    const float* fc_w       = (const float*)d_in[14];
    const float* fc_b       = (const float*)d_in[15];
    const float* cproj_w    = (const float*)d_in[16];
    const float* cproj_b    = (const float*)d_in[17];
    const float* ln_post_w  = (const float*)d_in[18];
    const float* ln_post_b  = (const float*)d_in[19];
    const float* proj_w     = (const float*)d_in[20];
    const float* head_w     = (const float*)d_in[21];
    const float* head_b     = (const float*)d_in[22];
    float* out = (float*)d_out;

    // -------- workspace layout --------
    char* ws = (char*)d_ws;
    size_t off = 0;
    float*    X     = (float*)(ws + off);    off += (size_t)MPAD * DD * 4;        // residual (fp32)
    ushort_t* Hb    = (ushort_t*)(ws + off); off += (size_t)MPAD * DD * 2;        // bf16 activations
    ushort_t* QKVb  = (ushort_t*)(ws + off); off += (size_t)MPAD * 2304 * 2;      // bf16 qkv
    ushort_t* Hmlp  = (ushort_t*)(ws + off); off += (size_t)MPAD * MLPD * 2;      // bf16 mlp / im2col
    float*    ScF   = (float*)(ws + off);    off += (size_t)(BB * NPATCH) * DD * 4; // patch gemm out
    float*    TmpF  = (float*)(ws + off);    off += (size_t)MPAD * DD * 4;        // assemble out
    ushort_t* Wb    = (ushort_t*)(ws + off); off += (size_t)85524480 * 2;         // bf16 weights
    float*  pooled  = (float*)(ws + off);    off += (size_t)BB * DD * 4;
    float*  z       = (float*)(ws + off);    off += (size_t)BB * PROJD * 4;

    ushort_t* convb  = Wb;
    ushort_t* qkvb   = convb  + 589824;
    ushort_t* aprojb = qkvb   + 21233664;
    ushort_t* fcb    = aprojb + 7077888;
    ushort_t* cprojb = fcb    + 28311552;

    // -------- zero split-K accumulators (kernel, not hipMemsetAsync:
    //          host memset nodes can break graph capture) --------
    zero_f32<<<(BB * PROJD + 255) / 256, 256, 0, stream>>>(z, BB * PROJD);
    zero_f32<<<(BB * NCLS + 255) / 256, 256, 0, stream>>>(out, BB * NCLS);

    // -------- weight conversions --------
    {
        long n;
        n = 589824;   f32_to_bf16<<<(n / 4 + 255) / 256, 256, 0, stream>>>(conv_w,  convb,  n);
        n = 21233664; f32_to_bf16<<<(n / 4 + 255) / 256, 256, 0, stream>>>(qkv_w,   qkvb,   n);
        n = 7077888;  f32_to_bf16<<<(n / 4 + 255) / 256, 256, 0, stream>>>(attn_pw, aprojb, n);
        n = 28311552; f32_to_bf16<<<(n / 4 + 255) / 256, 256, 0, stream>>>(fc_w,    fcb,    n);
        n = 28311552; f32_to_bf16<<<(n / 4 + 255) / 256, 256, 0, stream>>>(cproj_w, cprojb, n);
    }

    // -------- patch embed --------
    {
        int tot = BB * NPATCH * DD;
        im2col_bf16<<<(tot + 255) / 256, 256, 0, stream>>>(x, Hmlp);
        gemm_bf16_n64<<<dim3(DD / 64, 49), 256, 0, stream>>>(
            Hmlp, DD, convb, DD, nullptr, ScF, DD, DD, 0);
        int tot2 = MTOK * DD;
        assemble_kernel<<<(tot2 + 255) / 256, 256, 0, stream>>>(ScF, cls_token, pos_embed, TmpF);
        layernorm_rows<<<MTOK, 256, 0, stream>>>(TmpF, ln_pre_w, ln_pre_b, X);
    }

    // -------- transformer blocks --------
    for (int l = 0; l < NLAYER; l++) {
        layernorm_rows_bf16<<<MTOK, 256, 0, stream>>>(X, ln1_w + l * DD, ln1_b + l * DD, Hb);
        gemm_bf16<<<dim3(2304 / 128, MPAD / 128), 256, 0, stream>>>(
            Hb, DD, qkvb + (long)l * 2304 * DD, DD, qkv_b + l * 2304,
            QKVb, 2304, DD, 1 | 8);
        attn_fused<<<dim3(4, BB * NH), 256, 0, stream>>>(QKVb, Hb);
        gemm_bf16_n64<<<dim3(DD / 64, MPAD / 128), 256, 0, stream>>>(
            Hb, DD, aprojb + (long)l * DD * DD, DD, attn_pb + l * DD,
            X, DD, DD, 1 | 4);
        layernorm_rows_bf16<<<MTOK, 256, 0, stream>>>(X, ln2_w + l * DD, ln2_b + l * DD, Hb);
        gemm_bf16<<<dim3(MLPD / 128, MPAD / 128), 256, 0, stream>>>(
            Hb, DD, fcb + (long)l * MLPD * DD, DD, fc_b + l * MLPD,
            Hmlp, MLPD, DD, 1 | 2 | 8);
        gemm_bf16_n64<<<dim3(DD / 64, MPAD / 128), 256, 0, stream>>>(
            Hmlp, MLPD, cprojb + (long)l * DD * MLPD, MLPD, cproj_b + l * DD,
            X, DD, MLPD, 1 | 4);
    }

    // -------- head (split-K, latency-bound fix: 8/16 blocks -> 96/128) ----
    ln_post_cls<<<BB, 256, 0, stream>>>(X, ln_post_w, ln_post_b, pooled);
    gemm_nt_skm32<<<dim3(PROJD / 64, 1, DD / 64), 256, 0, stream>>>(
        pooled, DD, proj_w, DD, nullptr, z, PROJD, PROJD, 0);
    gemm_nt_skm32<<<dim3((NCLS + 63) / 64, 1, PROJD / 64), 256, 0, stream>>>(
        z, PROJD, head_w, PROJD, head_b, out, NCLS, NCLS, 1);
}